// Round 1
// baseline (217.579 us; speedup 1.0000x reference)
//
#include <hip/hip_runtime.h>
#include <math.h>

#define NB 60          // num_knots - k - 1 = 64 - 4
#define TROW 11        // padded knot row length: 3 + 5 + 3
#define K 3

__device__ __forceinline__ unsigned fkey(float f) {
    unsigned b = __float_as_uint(f);
    return (b & 0x80000000u) ? ~b : (b | 0x80000000u);
}
__device__ __forceinline__ float funkey(unsigned k) {
    return (k & 0x80000000u) ? __uint_as_float(k & 0x7fffffffu)
                             : __uint_as_float(~k);
}

__global__ void init_ws_k(unsigned* ws) {
    ws[0] = 0xFFFFFFFFu;  // running-min key (any key <= this)
    ws[1] = 0u;           // running-max key
}

__global__ __launch_bounds__(256) void minmax_k(const float* __restrict__ x, int n,
                                                unsigned* __restrict__ ws) {
    unsigned tid = blockIdx.x * blockDim.x + threadIdx.x;
    unsigned stride = gridDim.x * blockDim.x;
    float mn = INFINITY, mx = -INFINITY;
    for (unsigned i = tid; i < (unsigned)n; i += stride) {
        float v = x[i];
        mn = fminf(mn, v);
        mx = fmaxf(mx, v);
    }
    // wave64 butterfly reduce
    #pragma unroll
    for (int off = 32; off; off >>= 1) {
        mn = fminf(mn, __shfl_xor(mn, off));
        mx = fmaxf(mx, __shfl_xor(mx, off));
    }
    if ((threadIdx.x & 63u) == 0u) {
        atomicMin(&ws[0], fkey(mn));
        atomicMax(&ws[1], fkey(mx));
    }
}

__global__ __launch_bounds__(256) void bspline_k(const float* __restrict__ x,
                                                 const float* __restrict__ knots,
                                                 const unsigned* __restrict__ ws,
                                                 float* __restrict__ out,
                                                 int npoints) {
    __shared__ float T[NB * TROW];
    // Build padded knot table: T[i] = [k_i-1]*3 ++ knots[i..i+4] ++ [k_{i+4}+1]*3
    for (int t = threadIdx.x; t < NB * TROW; t += blockDim.x) {
        int i = t / TROW;
        int j = t - i * TROW;
        float v;
        if (j < K)            v = knots[i] - 1.0f;
        else if (j <= K + 4)  v = knots[i + j - K];
        else                  v = knots[i + 4] + 1.0f;
        T[t] = v;
    }
    __syncthreads();

    float mn = funkey(ws[0]);
    float mx = funkey(ws[1]);
    float inv = __builtin_amdgcn_rcpf(mx - mn + 1e-8f);

    unsigned total = (unsigned)npoints * NB;
    unsigned idx = blockIdx.x * blockDim.x + threadIdx.x;
    unsigned stride = gridDim.x * blockDim.x;

    for (; idx < total; idx += stride) {
        unsigned p = idx / (unsigned)NB;
        unsigned i = idx - p * (unsigned)NB;
        float xn = (x[p] - mn) * inv;

        const float* Trow = &T[i * TROW];
        // searchsorted_right over T reduces to counting seg entries <= xn:
        // bottom pads (k_i-1 <= 0 <= xn) always count (+3), top pads
        // (k_{i+4}+1 >= 1+1/57 > xn) never do.  ell = clip(3+c-1, 3, 6).
        float k0 = Trow[3], k1 = Trow[4], k2 = Trow[5], k3 = Trow[6], k4 = Trow[7];
        int c = (int)(k0 <= xn) + (int)(k1 <= xn) + (int)(k2 <= xn)
              + (int)(k3 <= xn) + (int)(k4 <= xn);
        int m = min(max(c - 1, 0), 3);
        int ell = 3 + m;

        float tm2 = Trow[ell - 2], tm1 = Trow[ell - 1], t0 = Trow[ell];
        float t1  = Trow[ell + 1], t2  = Trow[ell + 2], t3v = Trow[ell + 3];

        float den, w;
        // ---- j = 1 (hh0 = 1) ----
        den = t1 - t0;
        w = (den == 0.0f) ? 0.0f : __builtin_amdgcn_rcpf(den);
        float r0 = w * (t1 - xn);
        float r1 = w * (xn - t0);
        // ---- j = 2 ----
        den = t1 - tm1;                                   // n=1: hh0 = r0
        w = (den == 0.0f) ? 0.0f : r0 * __builtin_amdgcn_rcpf(den);
        r0 = w * (t1 - xn);
        float r1a = w * (xn - tm1);
        den = t2 - t0;                                    // n=2: hh1 = old r1
        w = (den == 0.0f) ? 0.0f : r1 * __builtin_amdgcn_rcpf(den);
        r1 = r1a + w * (t2 - xn);
        float r2 = w * (xn - t0);
        // ---- j = 3 ----
        float h0 = r0, h1 = r1, h2 = r2;
        den = t1 - tm2;                                   // n=1
        w = (den == 0.0f) ? 0.0f : h0 * __builtin_amdgcn_rcpf(den);
        r0 = w * (t1 - xn);
        r1 = w * (xn - tm2);
        den = t2 - tm1;                                   // n=2
        w = (den == 0.0f) ? 0.0f : h1 * __builtin_amdgcn_rcpf(den);
        r1 += w * (t2 - xn);
        r2 = w * (xn - tm1);
        den = t3v - t0;                                   // n=3
        w = (den == 0.0f) ? 0.0f : h2 * __builtin_amdgcn_rcpf(den);
        r2 += w * (t3v - xn);
        float r3 = w * (xn - t0);

        // res[2k - ell] = res[3 - m]
        float res = (m == 3) ? r0 : (m == 2) ? r1 : (m == 1) ? r2 : r3;
        if (isnan(res)) res = 0.0f;
        out[idx] = res;
    }
}

extern "C" void kernel_launch(void* const* d_in, const int* in_sizes, int n_in,
                              void* d_out, int out_size, void* d_ws, size_t ws_size,
                              hipStream_t stream) {
    const float* x     = (const float*)d_in[0];
    const float* knots = (const float*)d_in[1];
    // d_in[2] = degree, fixed at 3 (kernel is specialized for k=3)
    float* out = (float*)d_out;
    unsigned* ws = (unsigned*)d_ws;
    int npoints = in_sizes[0];

    hipLaunchKernelGGL(init_ws_k, dim3(1), dim3(1), 0, stream, ws);
    hipLaunchKernelGGL(minmax_k, dim3(256), dim3(256), 0, stream, x, npoints, ws);

    unsigned total = (unsigned)npoints * NB;
    const int BLOCK = 256, ITEMS = 4;
    unsigned blocks = (total + BLOCK * ITEMS - 1) / (BLOCK * ITEMS);
    hipLaunchKernelGGL(bspline_k, dim3(blocks), dim3(BLOCK), 0, stream,
                       x, knots, ws, out, npoints);
}

// Round 2
// 142.454 us; speedup vs baseline: 1.5274x; 1.5274x over previous
//
#include <hip/hip_runtime.h>
#include <math.h>

#define NK   64          // num knots
#define NBAS 60          // NK - K - 1
#define NBLK1 256        // partial-reduction blocks (fixed; main kernel reads exactly 256 partials)

// ---------------- kernel 1: per-block min/max partials -> ws ----------------
__global__ __launch_bounds__(256) void minmax_partial_k(const float* __restrict__ x, int n,
                                                        float2* __restrict__ part) {
    __shared__ float2 red[4];
    int t = threadIdx.x;
    float mn = INFINITY, mx = -INFINITY;
    for (unsigned i = blockIdx.x * 256u + t; i < (unsigned)n; i += 256u * NBLK1) {
        float v = x[i];
        mn = fminf(mn, v);
        mx = fmaxf(mx, v);
    }
    #pragma unroll
    for (int off = 32; off; off >>= 1) {
        mn = fminf(mn, __shfl_xor(mn, off));
        mx = fmaxf(mx, __shfl_xor(mx, off));
    }
    if ((t & 63) == 0) red[t >> 6] = make_float2(mn, mx);
    __syncthreads();
    if (t == 0) {
        mn = fminf(fminf(red[0].x, red[1].x), fminf(red[2].x, red[3].x));
        mx = fmaxf(fmaxf(red[0].y, red[1].y), fmaxf(red[2].y, red[3].y));
        part[blockIdx.x] = make_float2(mn, mx);
    }
}

// ---------------- kernel 2: coeff build + evaluate ----------------
// Each (basis i, piece m) is a cubic in xn. 240 cubics built per block via
// symbolic de Boor (poly coefficients, same den==0 guards as reference).
// Per output: m = clamp(S-1-ii, 0, 3), one b128 coeff read, 3-FMA Horner.
__global__ __launch_bounds__(256, 4) void bspline_main_k(const float* __restrict__ x,
                                                         const float* __restrict__ knots,
                                                         const float2* __restrict__ part,
                                                         float* __restrict__ out, int np) {
    __shared__ float4 scoef[4 * NBAS];   // [m*60 + i]
    __shared__ float2 spt[256];          // {xn, bitcast(S)} per point of this tile
    __shared__ float2 swred[4];
    int t = threadIdx.x;
    int blockStart = blockIdx.x * 256;

    // --- A1: final global min/max from the 256 partials ---
    float2 pr = part[t];
    float mn = pr.x, mx = pr.y;
    #pragma unroll
    for (int off = 32; off; off >>= 1) {
        mn = fminf(mn, __shfl_xor(mn, off));
        mx = fmaxf(mx, __shfl_xor(mx, off));
    }
    if ((t & 63) == 0) swred[t >> 6] = make_float2(mn, mx);

    // --- A2: symbolic de Boor -> cubic coefficients for (i, m), t < 240 ---
    if (t < 4 * NBAS) {
        int i = t >> 2;
        int m = t & 3;
        float k0 = knots[i], k1 = knots[i + 1], k2 = knots[i + 2],
              k3 = knots[i + 3], k4 = knots[i + 4];
        // padded row T: [k0-1]*3 ++ k0..k4 ++ [k4+1]*3 ; need T[ell-2 .. ell+3], ell=3+m
        float tq[6];
        #pragma unroll
        for (int d = 0; d < 6; ++d) {
            int q = m + 1 + d;                       // in [1, 9]
            int ci = q - 3; ci = ci < 0 ? 0 : (ci > 4 ? 4 : ci);
            float kv = ci == 0 ? k0 : ci == 1 ? k1 : ci == 2 ? k2 : ci == 3 ? k3 : k4;
            kv += (q < 3) ? -1.0f : ((q > 7) ? 1.0f : 0.0f);
            tq[d] = kv;
        }
        float tm2 = tq[0], tm1 = tq[1], tt0 = tq[2], tt1 = tq[3], tt2 = tq[4], tt3 = tq[5];

        // j=1
        float den = tt1 - tt0;
        float s = (den == 0.0f) ? 0.0f : __builtin_amdgcn_rcpf(den);
        float r0_0 = s * tt1, r0_1 = -s;             // s*(t1 - x)
        float r1_0 = -s * tt0, r1_1 = s;             // s*(x - t0)
        // j=2, n=1: w = s*r0 (deg1)
        den = tt1 - tm1; s = (den == 0.0f) ? 0.0f : __builtin_amdgcn_rcpf(den);
        float w0 = s * r0_0, w1 = s * r0_1;
        float a0_0 = tt1 * w0, a0_1 = tt1 * w1 - w0, a0_2 = -w1;   // r0 = w*(t1-x)
        float b1_0 = -tm1 * w0, b1_1 = w0 - tm1 * w1, b1_2 = w1;   // r1a = w*(x-tm1)
        // j=2, n=2: w = s*r1old
        den = tt2 - tt0; s = (den == 0.0f) ? 0.0f : __builtin_amdgcn_rcpf(den);
        w0 = s * r1_0; w1 = s * r1_1;
        float a1_0 = b1_0 + tt2 * w0, a1_1 = b1_1 + tt2 * w1 - w0, a1_2 = b1_2 - w1; // r1
        float a2_0 = -tt0 * w0, a2_1 = w0 - tt0 * w1, a2_2 = w1;                     // r2
        // j=3, n=1: w = s*a0 (deg2)
        den = tt1 - tm2; s = (den == 0.0f) ? 0.0f : __builtin_amdgcn_rcpf(den);
        w0 = s * a0_0; w1 = s * a0_1; float w2 = s * a0_2;
        float R0_0 = tt1 * w0, R0_1 = tt1 * w1 - w0, R0_2 = tt1 * w2 - w1, R0_3 = -w2;
        float R1_0 = -tm2 * w0, R1_1 = w0 - tm2 * w1, R1_2 = w1 - tm2 * w2, R1_3 = w2;
        // j=3, n=2: w = s*a1
        den = tt2 - tm1; s = (den == 0.0f) ? 0.0f : __builtin_amdgcn_rcpf(den);
        w0 = s * a1_0; w1 = s * a1_1; w2 = s * a1_2;
        R1_0 += tt2 * w0; R1_1 += tt2 * w1 - w0; R1_2 += tt2 * w2 - w1; R1_3 -= w2;
        float R2_0 = -tm1 * w0, R2_1 = w0 - tm1 * w1, R2_2 = w1 - tm1 * w2, R2_3 = w2;
        // j=3, n=3: w = s*a2
        den = tt3 - tt0; s = (den == 0.0f) ? 0.0f : __builtin_amdgcn_rcpf(den);
        w0 = s * a2_0; w1 = s * a2_1; w2 = s * a2_2;
        R2_0 += tt3 * w0; R2_1 += tt3 * w1 - w0; R2_2 += tt3 * w2 - w1; R2_3 -= w2;
        float R3_0 = -tt0 * w0, R3_1 = w0 - tt0 * w1, R3_2 = w1 - tt0 * w2, R3_3 = w2;

        // output poly = res[3 - m]
        float o0, o1, o2, o3;
        if (m == 0)      { o0 = R3_0; o1 = R3_1; o2 = R3_2; o3 = R3_3; }
        else if (m == 1) { o0 = R2_0; o1 = R2_1; o2 = R2_2; o3 = R2_3; }
        else if (m == 2) { o0 = R1_0; o1 = R1_1; o2 = R1_2; o3 = R1_3; }
        else             { o0 = R0_0; o1 = R0_1; o2 = R0_2; o3 = R0_3; }
        scoef[m * NBAS + i] = make_float4(o0, o1, o2, o3);
    }
    __syncthreads();

    // --- B: per-point xn and S = #{knots <= xn} (prefix, knots sorted) ---
    float2 ra = swred[0], rb = swred[1], rc = swred[2], rd = swred[3];
    mn = fminf(fminf(ra.x, rb.x), fminf(rc.x, rd.x));
    mx = fmaxf(fmaxf(ra.y, rb.y), fmaxf(rc.y, rd.y));
    float inv = __builtin_amdgcn_rcpf(mx - mn + 1e-8f);
    int p = blockStart + t;
    int pc = p < np ? p : (np - 1);
    float xn = (x[pc] - mn) * inv;
    int S = 0;
    #pragma unroll
    for (int j = 0; j < NK; ++j) S += (knots[j] <= xn) ? 1 : 0;
    spt[t] = make_float2(xn, __int_as_float(S));
    __syncthreads();

    // --- C: write 256*60 outputs, coalesced; idx = it*256 + t ---
    int pl = t / NBAS;             // local point
    int ii = t - pl * NBAS;        // basis index
    int npl = np - blockStart;     // valid points in this tile
    float* po = out + (long long)blockStart * NBAS + t;
    #pragma unroll 4
    for (int it = 0; it < NBAS; ++it) {
        if (pl < npl) {
            float2 v = spt[pl];
            int S2 = __float_as_int(v.y);
            int m = S2 - 1 - ii; m = m < 0 ? 0 : (m > 3 ? 3 : m);
            float4 cf = scoef[m * NBAS + ii];
            float xv = v.x;
            float r = fmaf(fmaf(fmaf(cf.w, xv, cf.z), xv, cf.y), xv, cf.x);
            __builtin_nontemporal_store(r, po);
        }
        po += 256;
        ii += 16; pl += 4;
        if (ii >= NBAS) { ii -= NBAS; pl += 1; }
    }
}

extern "C" void kernel_launch(void* const* d_in, const int* in_sizes, int n_in,
                              void* d_out, int out_size, void* d_ws, size_t ws_size,
                              hipStream_t stream) {
    const float* x     = (const float*)d_in[0];
    const float* knots = (const float*)d_in[1];
    // d_in[2] = degree, specialized to 3
    float* out = (float*)d_out;
    float2* part = (float2*)d_ws;          // 256 * 8 B = 2 KB of scratch
    int np = in_sizes[0];

    hipLaunchKernelGGL(minmax_partial_k, dim3(NBLK1), dim3(256), 0, stream, x, np, part);
    int blocks = (np + 255) / 256;
    hipLaunchKernelGGL(bspline_main_k, dim3(blocks), dim3(256), 0, stream,
                       x, knots, part, out, np);
}